// Round 9
// baseline (162.462 us; speedup 1.0000x reference)
//
#include <hip/hip_runtime.h>
#include <hip/hip_bf16.h>
#include <cstdint>

// Problem constants
#define Bb  8
#define Tt  2048
#define Cc  256
#define FDd 256
#define Kk  128
#define Vv  256
#define BT  (Bb * Tt)
#define NTRI 136          // 16*17/2 lower-triangular 128x128 blocks per batch

#define INV_SQRT_K 0.08838834764831845f  // 1/sqrt(128)

typedef __bf16 bf16x8 __attribute__((ext_vector_type(8)));
typedef __bf16 bf16x4 __attribute__((ext_vector_type(4)));
typedef float  f32x4  __attribute__((ext_vector_type(4)));

// async global->LDS, 16B per lane. LDS dest = wave-uniform base + lane*16.
__device__ __forceinline__ void gload16(const void* g, void* l) {
  __builtin_amdgcn_global_load_lds(
      (const __attribute__((address_space(1))) void*)g,
      (__attribute__((address_space(3))) void*)l, 16, 0, 0);
}

// ---------------------------------------------------------------------------
// prepw: fused prep + wprep (unchanged — validated).
// ---------------------------------------------------------------------------
__global__ __launch_bounds__(256) void prepw_kernel(
    const float4* __restrict__ inp4, const float4* __restrict__ feat4,
    float4* __restrict__ out4, bf16x4* __restrict__ inpB4,
    bf16x4* __restrict__ featB4,
    const float* __restrict__ Wq, const float* __restrict__ Wk,
    const float* __restrict__ Wv, __bf16* __restrict__ Wqt,
    __bf16* __restrict__ Wkt, __bf16* __restrict__ Wvt)
{
  if (blockIdx.x < 4096) {
    const int g = blockIdx.x * 256 + threadIdx.x;   // 0 .. BT*64
    const int row = g >> 6, c = g & 63;
    const float4 x = inp4[g];
    out4[(size_t)row * 128 + c] = x;
    bf16x4 xb; xb[0] = (__bf16)x.x; xb[1] = (__bf16)x.y; xb[2] = (__bf16)x.z; xb[3] = (__bf16)x.w;
    inpB4[g] = xb;
    const float4 f = feat4[g];
    bf16x4 fb; fb[0] = (__bf16)f.x; fb[1] = (__bf16)f.y; fb[2] = (__bf16)f.z; fb[3] = (__bf16)f.w;
    featB4[g] = fb;
  } else {
    const int g = (blockIdx.x - 4096) * 256 + threadIdx.x;
    if (g < 65536) {                       // Wq: 512x128 -> Wqt 128x512
      const int n = g >> 9, k = g & 511;
      Wqt[g] = (__bf16)Wq[k * 128 + n];
    } else if (g < 98304) {                // Wk: 256x128 -> Wkt 128x256
      const int h = g - 65536;
      const int n = h >> 8, k = h & 255;
      Wkt[h] = (__bf16)Wk[k * 128 + n];
    } else {                               // Wv: 256x256 -> Wvt 256x256
      const int h = g - 98304;
      const int n = h >> 8, k = h & 255;
      Wvt[h] = (__bf16)Wv[k * 256 + n];
    }
  }
}

// ---------------------------------------------------------------------------
// qkv v3: double-buffered staging (validated R8).
// ---------------------------------------------------------------------------
__global__ __launch_bounds__(256, 2) void qkv_mfma_kernel(
    const __bf16* __restrict__ inpB, const __bf16* __restrict__ featB,
    const __bf16* __restrict__ Wqt, const __bf16* __restrict__ Wkt,
    const __bf16* __restrict__ Wvt,
    const float* __restrict__ bq, const float* __restrict__ bk,
    const float* __restrict__ bv,
    __bf16* __restrict__ qb, __bf16* __restrict__ kb, __bf16* __restrict__ vT)
{
  __shared__ __bf16 At[2][128 * 64];
  __shared__ __bf16 Bt[2][128 * 64];
  const int panel = blockIdx.y;
  const int m0 = blockIdx.x * 128;
  const int lane = threadIdx.x & 63, wave = threadIdx.x >> 6;
  const int cl = lane & 15, quad = lane >> 4;
  const int jl0 = (wave >> 1) * 64;    // wave m-offset in tile
  const int vl0 = (wave & 1) * 64;     // wave n-offset in tile

  const __bf16* Wt; const float* bias; int kblocks;
  if (panel == 0)      { Wt = Wqt; bias = bq; kblocks = 8; }
  else if (panel == 1) { Wt = Wkt; bias = bk; kblocks = 4; }
  else                 { Wt = Wvt + (size_t)(panel - 2) * 128 * 256;
                         bias = bv + (panel - 2) * 128; kblocks = 4; }
  const int Kd = kblocks * 64;

  const int lrow = lane >> 3;
  const int lchunk = ((lane & 7) ^ lrow) * 8;      // element offset of 16B chunk

  f32x4 acc[4][4];
#pragma unroll
  for (int mt = 0; mt < 4; ++mt)
#pragma unroll
    for (int nt = 0; nt < 4; ++nt) acc[mt][nt] = (f32x4){0.f, 0.f, 0.f, 0.f};

  // prologue: stage step 0 into buf 0
  {
    const __bf16* Asrc = inpB;
#pragma unroll
    for (int t = 0; t < 4; ++t) {
      const int r0 = wave * 32 + t * 8;
      gload16(Asrc + (size_t)(m0 + r0 + lrow) * 256 + lchunk, At[0] + r0 * 64);
      gload16(Wt + (size_t)(r0 + lrow) * Kd + lchunk, Bt[0] + r0 * 64);
    }
  }
  __syncthreads();

  int buf = 0;
  for (int kb = 0; kb < kblocks; ++kb) {
    // ---- prefetch next step into buf^1 (flies under compute) ----
    if (kb + 1 < kblocks) {
      const int kn = kb + 1;
      const __bf16* Asrc = (panel == 0 && kn >= 4) ? featB : inpB;
      const int koff = (panel == 0 && kn >= 4) ? (kn - 4) * 64 : kn * 64;
#pragma unroll
      for (int t = 0; t < 4; ++t) {
        const int r0 = wave * 32 + t * 8;
        gload16(Asrc + (size_t)(m0 + r0 + lrow) * 256 + koff + lchunk, At[buf ^ 1] + r0 * 64);
        gload16(Wt + (size_t)(r0 + lrow) * Kd + kn * 64 + lchunk, Bt[buf ^ 1] + r0 * 64);
      }
    }
    // ---- compute current buffer ----
#pragma unroll
    for (int ks = 0; ks < 2; ++ks) {
      bf16x8 af[4], bfr[4];
#pragma unroll
      for (int mt = 0; mt < 4; ++mt) {
        const int jlr = jl0 + mt * 16 + cl;
        af[mt] = *(const bf16x8*)(At[buf] + jlr * 64 + (((ks * 4 + quad) ^ (jlr & 7)) * 8));
      }
#pragma unroll
      for (int nt = 0; nt < 4; ++nt) {
        const int vlr = vl0 + nt * 16 + cl;
        bfr[nt] = *(const bf16x8*)(Bt[buf] + vlr * 64 + (((ks * 4 + quad) ^ (vlr & 7)) * 8));
      }
#pragma unroll
      for (int mt = 0; mt < 4; ++mt)
#pragma unroll
        for (int nt = 0; nt < 4; ++nt)
          acc[mt][nt] = __builtin_amdgcn_mfma_f32_16x16x32_bf16(af[mt], bfr[nt], acc[mt][nt], 0, 0, 0);
    }
    __syncthreads();                   // drains prefetch vmcnt; buf^1 ready
    buf ^= 1;
  }

  if (panel < 2) {
    __bf16* dst = (panel == 0) ? qb : kb;
    const float scale = (panel == 0) ? INV_SQRT_K : 1.0f;
#pragma unroll
    for (int mt = 0; mt < 4; ++mt) {
      const int row = m0 + jl0 + mt * 16 + quad * 4;
#pragma unroll
      for (int nt = 0; nt < 4; ++nt) {
        const int col = vl0 + nt * 16 + cl;
        const float bs = bias[col];
#pragma unroll
        for (int r = 0; r < 4; ++r)
          dst[(size_t)(row + r) * Kk + col] = (__bf16)((acc[mt][nt][r] + bs) * scale);
      }
    }
  } else {
    const int b = m0 >> 11;            // 128-row blocks never straddle a batch
#pragma unroll
    for (int mt = 0; mt < 4; ++mt) {
      const int t0 = (m0 & (Tt - 1)) + jl0 + mt * 16 + quad * 4;
#pragma unroll
      for (int nt = 0; nt < 4; ++nt) {
        const int vcol = (panel - 2) * 128 + vl0 + nt * 16 + cl;
        const float bs = bias[vl0 + nt * 16 + cl];
        bf16x4 v4;
#pragma unroll
        for (int r = 0; r < 4; ++r) v4[r] = (__bf16)(acc[mt][nt][r] + bs);
        *(bf16x4*)(vT + (size_t)(b * Vv + vcol) * Tt + t0) = v4;
      }
    }
  }
}

// ---------------------------------------------------------------------------
// sexp v3: expS = exp(Q.K^T) for lower-tri 128x128 blocks.
//   (unchanged — validated R5-R8; P-write XOR swizzle, batch = blockIdx.x)
// ---------------------------------------------------------------------------
__global__ __launch_bounds__(256, 2) void sexp_kernel(
    const __bf16* __restrict__ qb, const __bf16* __restrict__ kb,
    __bf16* __restrict__ expS, float* __restrict__ partialD)
{
  __shared__ __bf16 tiles[2 * 128 * 128];   // Qtile | Ktile; reused as fp32 P
  __shared__ float lcs[4][64];
  __bf16* Qtile = tiles;
  __bf16* Ktile = tiles + 128 * 128;
  float*  P     = (float*)tiles;            // 128x128 fp32 = 64 KB

  const int b = blockIdx.x, l = blockIdx.y;  // batch fast -> XCD = b
  int jt = 0, base = 0;
  while (base + jt + 1 <= l) { base += jt + 1; ++jt; }   // uniform, <=16 iters
  const int it = l - base;

  const int lane = threadIdx.x & 63, wave = threadIdx.x >> 6;
  const int cl = lane & 15, quad = lane >> 4;
  const int jl0 = (wave >> 1) * 64;
  const int il0 = (wave & 1) * 64;
  const size_t rowbase = (size_t)b * Tt;

  // staging: 4 rows per gload16 (16 chunks/row); lane L -> row +L>>4,
  // slot L&15 holds source chunk (L&15)^(row&7).
  {
    const int srow = lane >> 4;          // 0..3
    const int cslot = lane & 15;
    const __bf16* qsrc = qb + (rowbase + jt * 128) * Kk;
    const __bf16* ksrc = kb + (rowbase + it * 128) * Kk;
#pragma unroll
    for (int t = 0; t < 8; ++t) {
      const int r0 = wave * 32 + t * 4;
      const int row = r0 + srow;
      const int cg = (cslot ^ (row & 7)) * 8;
      gload16(qsrc + (size_t)row * Kk + cg, Qtile + r0 * 128);
      gload16(ksrc + (size_t)row * Kk + cg, Ktile + r0 * 128);
    }
  }
  __syncthreads();

  f32x4 acc[4][4];
#pragma unroll
  for (int mt = 0; mt < 4; ++mt)
#pragma unroll
    for (int nt = 0; nt < 4; ++nt) acc[mt][nt] = (f32x4){0.f, 0.f, 0.f, 0.f};

#pragma unroll
  for (int s = 0; s < 4; ++s) {
    bf16x8 af[4], bfr[4];
#pragma unroll
    for (int mt = 0; mt < 4; ++mt) {
      const int jlr = jl0 + mt * 16 + cl;
      af[mt] = *(const bf16x8*)(Qtile + jlr * 128 + (((s * 4 + quad) ^ (jlr & 7)) * 8));
    }
#pragma unroll
    for (int nt = 0; nt < 4; ++nt) {
      const int ilr = il0 + nt * 16 + cl;
      bfr[nt] = *(const bf16x8*)(Ktile + ilr * 128 + (((s * 4 + quad) ^ (ilr & 7)) * 8));
    }
#pragma unroll
    for (int mt = 0; mt < 4; ++mt)
#pragma unroll
      for (int nt = 0; nt < 4; ++nt)
        acc[mt][nt] = __builtin_amdgcn_mfma_f32_16x16x32_bf16(af[mt], bfr[nt], acc[mt][nt], 0, 0, 0);
  }
  __syncthreads();                       // tiles free -> reuse as P

  // masked exp -> fp32 P (swizzled writes) + column sums of rounded values
  const bool diag = (it == jt);
  float cs[4] = {0.f, 0.f, 0.f, 0.f};
#pragma unroll
  for (int mt = 0; mt < 4; ++mt) {
    const int jl = jl0 + mt * 16 + quad * 4;
#pragma unroll
    for (int nt = 0; nt < 4; ++nt) {
      const int il = il0 + nt * 16 + cl;
#pragma unroll
      for (int r = 0; r < 4; ++r) {
        float p = __expf(acc[mt][nt][r]);
        if (diag && il > (jl + r)) p = 0.f;   // mask i > j (same-tile coords)
        cs[nt] += (float)(__bf16)p;           // what pass B will consume
        const int row = jl + r;
        P[row * 128 + (il ^ (((row >> 2) & 1) << 4))] = p;
      }
    }
  }
#pragma unroll
  for (int nt = 0; nt < 4; ++nt) {
    cs[nt] += __shfl_xor(cs[nt], 16);
    cs[nt] += __shfl_xor(cs[nt], 32);
  }
  if (quad == 0) {
#pragma unroll
    for (int nt = 0; nt < 4; ++nt) lcs[wave][nt * 16 + cl] = cs[nt];
  }
  __syncthreads();

  // coalesced bf16 store: 4 rows per pass, lane L -> row +L>>4, 8 elems.
  __bf16* slot = expS + ((size_t)(b * NTRI + l)) * (128 * 128);
  {
    const int srow = lane >> 4;
    const int c0 = (lane & 15) * 8;
#pragma unroll
    for (int t = 0; t < 8; ++t) {
      const int row = wave * 32 + t * 4 + srow;
      const int c0p = c0 ^ (((row >> 2) & 1) << 4);
      const f32x4 p0 = *(const f32x4*)(P + row * 128 + c0p);
      const f32x4 p1 = *(const f32x4*)(P + row * 128 + c0p + 4);
      bf16x8 pb;
#pragma unroll
      for (int u = 0; u < 4; ++u) { pb[u] = (__bf16)p0[u]; pb[4 + u] = (__bf16)p1[u]; }
      *(bf16x8*)(slot + (size_t)row * 128 + c0) = pb;
    }
  }

  const int tid = threadIdx.x;
  if (tid < 128) {                      // block column c = tid
    const int w0 = (tid < 64) ? 0 : 1;  // waves {0,2} cols [0,64), {1,3} [64,128)
    const int lc = tid & 63;
    const float s = lcs[w0][lc] + lcs[w0 + 2][lc];
    partialD[((size_t)b * 16 + jt) * Tt + it * 128 + tid] = s;
  }
}

// ---------------------------------------------------------------------------
// dreduce: recipD[b][i] = 1 / sum_jt partialD[b][jt][i].  grid 64 x 256.
// ---------------------------------------------------------------------------
__global__ __launch_bounds__(256) void dreduce_kernel(
    const float* __restrict__ partialD, float* __restrict__ recipD)
{
  const int g = blockIdx.x * 256 + threadIdx.x;  // 0..16383
  const int b = g >> 11, i = g & (Tt - 1);
  float s = 0.f;
#pragma unroll
  for (int jt = 0; jt < 16; ++jt) s += partialD[((size_t)b * 16 + jt) * Tt + i];
  recipD[g] = 1.0f / s;
}

// ---------------------------------------------------------------------------
// pvgemm v10: v9 + inline V-scaling with register-prefetched rec.
//   dvscale's 34 MB vT round-trip eliminated: B fragments scaled after the
//   LDS read with dvscale's exact rounding chain (bf16 -> f32*rec -> bf16).
//   rec values for step kb+1 are loaded into registers during the prefetch
//   phase (off the critical path — fixes R5's failure); at 4 blocks/CU the
//   scale VALU hides under co-resident waves' MFMAs.
// ---------------------------------------------------------------------------
__global__ __launch_bounds__(256, 4) void pvgemm_kernel(
    const __bf16* __restrict__ expS, const __bf16* __restrict__ vT,
    const float* __restrict__ recipD, float* __restrict__ out)
{
  __shared__ __bf16 At[2][64 * 64];    // [jlocal 64][k 64], chunks swizzled
  __shared__ __bf16 Bt[2][64 * 64];    // [vlocal 64][k 64], chunks swizzled
  const int b = blockIdx.x;            // XCD affinity (gridDim.x = 8)
  const int y = (int)blockIdx.y;       // 0..127
  const int jt64 = 31 - (y >> 2);      // long strips first (LPT)
  const int nq = y & 3;                // 64-col quarter
  const int lane = threadIdx.x & 63, wave = threadIdx.x >> 6;
  const int cl = lane & 15, quad = lane >> 4;
  const int jl0 = (wave >> 1) * 32;    // wave m-offset in tile
  const int vl0 = (wave & 1) * 32;     // wave n-offset in tile
  const int lrow = lane >> 3;
  const int lchunk = ((lane & 7) ^ lrow) * 8;      // element offset of 16B chunk
  const __bf16* vbase = vT + ((size_t)b * Vv + nq * 64) * Tt;
  const float* rbase = recipD + (size_t)b * Tt;

  const int jt128 = jt64 >> 1;
  const int rowoff = (jt64 & 1) * 64;             // row offset inside 128-tile
  const int ksteps = jt64 + 1;                    // BK=64 steps
  const size_t tribase = (size_t)(b * NTRI + (jt128 * (jt128 + 1)) / 2) * 16384;

  f32x4 acc[2][2];
#pragma unroll
  for (int mt = 0; mt < 2; ++mt)
#pragma unroll
    for (int nt = 0; nt < 2; ++nt) acc[mt][nt] = (f32x4){0.f, 0.f, 0.f, 0.f};

  // prologue: stage step 0 into buf 0 + rec for step 0 into registers
  f32x4 rnxt[2][2];                    // [ks][lo/hi half of 8 i-values]
#pragma unroll
  for (int t = 0; t < 2; ++t) {
    const int r0 = wave * 16 + t * 8;
    gload16(expS + tribase + (size_t)(rowoff + r0 + lrow) * 128 + lchunk,
            At[0] + r0 * 64);
    gload16(vbase + (size_t)(r0 + lrow) * Tt + lchunk, Bt[0] + r0 * 64);
  }
#pragma unroll
  for (int ks = 0; ks < 2; ++ks) {
    rnxt[ks][0] = *(const f32x4*)(rbase + (ks * 4 + quad) * 8);
    rnxt[ks][1] = *(const f32x4*)(rbase + (ks * 4 + quad) * 8 + 4);
  }
  __syncthreads();                   // step 0 staged

  int buf = 0;
  for (int kb = 0; kb < ksteps; ++kb) {
    const f32x4 rc00 = rnxt[0][0], rc01 = rnxt[0][1];
    const f32x4 rc10 = rnxt[1][0], rc11 = rnxt[1][1];
    // ---- issue next step's stage into buf^1 + next rec (under compute) ----
    if (kb + 1 < ksteps) {
      const int kn = kb + 1;
      const __bf16* Ag = expS + tribase + (size_t)(kn >> 1) * 16384
                       + (size_t)rowoff * 128 + (kn & 1) * 64;
      const int i0n = kn * 64;
#pragma unroll
      for (int t = 0; t < 2; ++t) {
        const int r0 = wave * 16 + t * 8;
        gload16(Ag + (size_t)(r0 + lrow) * 128 + lchunk, At[buf ^ 1] + r0 * 64);
        gload16(vbase + (size_t)(r0 + lrow) * Tt + i0n + lchunk, Bt[buf ^ 1] + r0 * 64);
      }
      const float* rstep = rbase + i0n;
#pragma unroll
      for (int ks = 0; ks < 2; ++ks) {
        rnxt[ks][0] = *(const f32x4*)(rstep + (ks * 4 + quad) * 8);
        rnxt[ks][1] = *(const f32x4*)(rstep + (ks * 4 + quad) * 8 + 4);
      }
    }
    // ---- compute current buffer (B scaled by rec, dvscale chain) ----
#pragma unroll
    for (int ks = 0; ks < 2; ++ks) {
      const f32x4 ra = ks ? rc10 : rc00;
      const f32x4 rb = ks ? rc11 : rc01;
      bf16x8 af[2], bfr[2];
#pragma unroll
      for (int mt = 0; mt < 2; ++mt) {
        const int jlr = jl0 + mt * 16 + cl;
        af[mt] = *(const bf16x8*)(At[buf] + jlr * 64 + (((ks * 4 + quad) ^ (jlr & 7)) * 8));
      }
#pragma unroll
      for (int nt = 0; nt < 2; ++nt) {
        const int vlr = vl0 + nt * 16 + cl;
        bfr[nt] = *(const bf16x8*)(Bt[buf] + vlr * 64 + (((ks * 4 + quad) ^ (vlr & 7)) * 8));
#pragma unroll
        for (int u = 0; u < 4; ++u) {
          bfr[nt][u]     = (__bf16)((float)bfr[nt][u]     * ra[u]);
          bfr[nt][4 + u] = (__bf16)((float)bfr[nt][4 + u] * rb[u]);
        }
      }
#pragma unroll
      for (int mt = 0; mt < 2; ++mt)
#pragma unroll
        for (int nt = 0; nt < 2; ++nt)
          acc[mt][nt] = __builtin_amdgcn_mfma_f32_16x16x32_bf16(af[mt], bfr[nt], acc[mt][nt], 0, 0, 0);
    }
    __syncthreads();                 // drains prefetch vmcnt; buf^1 ready
    buf ^= 1;
  }

  // ---- epilogue: fp32 stores to out[:, 256:512] (disjoint region) ----
  float* orow = out + ((size_t)b * Tt + jt64 * 64 + jl0) * (size_t)(Cc + Vv)
              + Cc + nq * 64 + vl0;
#pragma unroll
  for (int mt = 0; mt < 2; ++mt)
#pragma unroll
    for (int nt = 0; nt < 2; ++nt)
#pragma unroll
      for (int r = 0; r < 4; ++r)
        orow[(size_t)(mt * 16 + quad * 4 + r) * (Cc + Vv) + nt * 16 + cl] = acc[mt][nt][r];
}

// ---------------------------------------------------------------------------
extern "C" void kernel_launch(void* const* d_in, const int* in_sizes, int n_in,
                              void* d_out, int out_size, void* d_ws, size_t ws_size,
                              hipStream_t stream) {
  const float* inp  = (const float*)d_in[0];
  const float* feat = (const float*)d_in[1];
  const float* Wq   = (const float*)d_in[2];
  const float* bq   = (const float*)d_in[3];
  const float* Wk   = (const float*)d_in[4];
  const float* bk   = (const float*)d_in[5];
  const float* Wv   = (const float*)d_in[6];
  const float* bv   = (const float*)d_in[7];
  float* out = (float*)d_out;

  // ws layout (~71 MB):
  //  inpB 8M | featB 8M | qb 4M | kb 4M | vT 8M | Wqt/Wkt/Wvt 320K |
  //  partialD 2M @33M | recipD 64K @35M | expS 34.8M @36M
  char* ws = (char*)d_ws;
  __bf16* inpB   = (__bf16*)(ws);
  __bf16* featB  = (__bf16*)(ws + (8u << 20));
  __bf16* qb     = (__bf16*)(ws + (16u << 20));
  __bf16* kb     = (__bf16*)(ws + (20u << 20));
  __bf16* vT     = (__bf16*)(ws + (24u << 20));
  __bf16* Wqt    = (__bf16*)(ws + (32u << 20));
  __bf16* Wkt    = (__bf16*)(ws + (32u << 20) + (128u << 10));
  __bf16* Wvt    = (__bf16*)(ws + (32u << 20) + (192u << 10));
  float*  partialD = (float*)(ws + (33u << 20));
  float*  recipD   = (float*)(ws + (35u << 20));
  __bf16* expS     = (__bf16*)(ws + (36u << 20));

  prepw_kernel<<<dim3(4096 + 640), 256, 0, stream>>>(
      (const float4*)inp, (const float4*)feat, (float4*)out,
      (bf16x4*)inpB, (bf16x4*)featB, Wq, Wk, Wv, Wqt, Wkt, Wvt);
  qkv_mfma_kernel<<<dim3(BT / 128, 4), 256, 0, stream>>>(
      inpB, featB, Wqt, Wkt, Wvt, bq, bk, bv, qb, kb, vT);
  sexp_kernel<<<dim3(Bb, NTRI), 256, 0, stream>>>(qb, kb, expS, partialD);
  dreduce_kernel<<<dim3(BT / 256), 256, 0, stream>>>(partialD, recipD);
  pvgemm_kernel<<<dim3(Bb, 128), 256, 0, stream>>>(expS, vT, recipD, out);
}

// Round 10
// 154.638 us; speedup vs baseline: 1.0506x; 1.0506x over previous
//
#include <hip/hip_runtime.h>
#include <hip/hip_bf16.h>
#include <cstdint>

// Problem constants
#define Bb  8
#define Tt  2048
#define Cc  256
#define FDd 256
#define Kk  128
#define Vv  256
#define BT  (Bb * Tt)
#define NTRI 136          // 16*17/2 lower-triangular 128x128 blocks per batch

#define INV_SQRT_K 0.08838834764831845f  // 1/sqrt(128)

typedef __bf16 bf16x8 __attribute__((ext_vector_type(8)));
typedef __bf16 bf16x4 __attribute__((ext_vector_type(4)));
typedef float  f32x4  __attribute__((ext_vector_type(4)));

// async global->LDS, 16B per lane. LDS dest = wave-uniform base + lane*16.
__device__ __forceinline__ void gload16(const void* g, void* l) {
  __builtin_amdgcn_global_load_lds(
      (const __attribute__((address_space(1))) void*)g,
      (__attribute__((address_space(3))) void*)l, 16, 0, 0);
}

// ---------------------------------------------------------------------------
// prepw: fused prep + wprep (validated).
// ---------------------------------------------------------------------------
__global__ __launch_bounds__(256) void prepw_kernel(
    const float4* __restrict__ inp4, const float4* __restrict__ feat4,
    float4* __restrict__ out4, bf16x4* __restrict__ inpB4,
    bf16x4* __restrict__ featB4,
    const float* __restrict__ Wq, const float* __restrict__ Wk,
    const float* __restrict__ Wv, __bf16* __restrict__ Wqt,
    __bf16* __restrict__ Wkt, __bf16* __restrict__ Wvt)
{
  if (blockIdx.x < 4096) {
    const int g = blockIdx.x * 256 + threadIdx.x;   // 0 .. BT*64
    const int row = g >> 6, c = g & 63;
    const float4 x = inp4[g];
    out4[(size_t)row * 128 + c] = x;
    bf16x4 xb; xb[0] = (__bf16)x.x; xb[1] = (__bf16)x.y; xb[2] = (__bf16)x.z; xb[3] = (__bf16)x.w;
    inpB4[g] = xb;
    const float4 f = feat4[g];
    bf16x4 fb; fb[0] = (__bf16)f.x; fb[1] = (__bf16)f.y; fb[2] = (__bf16)f.z; fb[3] = (__bf16)f.w;
    featB4[g] = fb;
  } else {
    const int g = (blockIdx.x - 4096) * 256 + threadIdx.x;
    if (g < 65536) {                       // Wq: 512x128 -> Wqt 128x512
      const int n = g >> 9, k = g & 511;
      Wqt[g] = (__bf16)Wq[k * 128 + n];
    } else if (g < 98304) {                // Wk: 256x128 -> Wkt 128x256
      const int h = g - 65536;
      const int n = h >> 8, k = h & 255;
      Wkt[h] = (__bf16)Wk[k * 128 + n];
    } else {                               // Wv: 256x256 -> Wvt 256x256
      const int h = g - 98304;
      const int n = h >> 8, k = h & 255;
      Wvt[h] = (__bf16)Wv[k * 256 + n];
    }
  }
}

// ---------------------------------------------------------------------------
// qkv v3: double-buffered staging (validated R8).
// ---------------------------------------------------------------------------
__global__ __launch_bounds__(256, 2) void qkv_mfma_kernel(
    const __bf16* __restrict__ inpB, const __bf16* __restrict__ featB,
    const __bf16* __restrict__ Wqt, const __bf16* __restrict__ Wkt,
    const __bf16* __restrict__ Wvt,
    const float* __restrict__ bq, const float* __restrict__ bk,
    const float* __restrict__ bv,
    __bf16* __restrict__ qb, __bf16* __restrict__ kb, __bf16* __restrict__ vT)
{
  __shared__ __bf16 At[2][128 * 64];
  __shared__ __bf16 Bt[2][128 * 64];
  const int panel = blockIdx.y;
  const int m0 = blockIdx.x * 128;
  const int lane = threadIdx.x & 63, wave = threadIdx.x >> 6;
  const int cl = lane & 15, quad = lane >> 4;
  const int jl0 = (wave >> 1) * 64;    // wave m-offset in tile
  const int vl0 = (wave & 1) * 64;     // wave n-offset in tile

  const __bf16* Wt; const float* bias; int kblocks;
  if (panel == 0)      { Wt = Wqt; bias = bq; kblocks = 8; }
  else if (panel == 1) { Wt = Wkt; bias = bk; kblocks = 4; }
  else                 { Wt = Wvt + (size_t)(panel - 2) * 128 * 256;
                         bias = bv + (panel - 2) * 128; kblocks = 4; }
  const int Kd = kblocks * 64;

  const int lrow = lane >> 3;
  const int lchunk = ((lane & 7) ^ lrow) * 8;      // element offset of 16B chunk

  f32x4 acc[4][4];
#pragma unroll
  for (int mt = 0; mt < 4; ++mt)
#pragma unroll
    for (int nt = 0; nt < 4; ++nt) acc[mt][nt] = (f32x4){0.f, 0.f, 0.f, 0.f};

  // prologue: stage step 0 into buf 0
  {
    const __bf16* Asrc = inpB;
#pragma unroll
    for (int t = 0; t < 4; ++t) {
      const int r0 = wave * 32 + t * 8;
      gload16(Asrc + (size_t)(m0 + r0 + lrow) * 256 + lchunk, At[0] + r0 * 64);
      gload16(Wt + (size_t)(r0 + lrow) * Kd + lchunk, Bt[0] + r0 * 64);
    }
  }
  __syncthreads();

  int buf = 0;
  for (int kb = 0; kb < kblocks; ++kb) {
    // ---- prefetch next step into buf^1 (flies under compute) ----
    if (kb + 1 < kblocks) {
      const int kn = kb + 1;
      const __bf16* Asrc = (panel == 0 && kn >= 4) ? featB : inpB;
      const int koff = (panel == 0 && kn >= 4) ? (kn - 4) * 64 : kn * 64;
#pragma unroll
      for (int t = 0; t < 4; ++t) {
        const int r0 = wave * 32 + t * 8;
        gload16(Asrc + (size_t)(m0 + r0 + lrow) * 256 + koff + lchunk, At[buf ^ 1] + r0 * 64);
        gload16(Wt + (size_t)(r0 + lrow) * Kd + kn * 64 + lchunk, Bt[buf ^ 1] + r0 * 64);
      }
    }
    // ---- compute current buffer ----
#pragma unroll
    for (int ks = 0; ks < 2; ++ks) {
      bf16x8 af[4], bfr[4];
#pragma unroll
      for (int mt = 0; mt < 4; ++mt) {
        const int jlr = jl0 + mt * 16 + cl;
        af[mt] = *(const bf16x8*)(At[buf] + jlr * 64 + (((ks * 4 + quad) ^ (jlr & 7)) * 8));
      }
#pragma unroll
      for (int nt = 0; nt < 4; ++nt) {
        const int vlr = vl0 + nt * 16 + cl;
        bfr[nt] = *(const bf16x8*)(Bt[buf] + vlr * 64 + (((ks * 4 + quad) ^ (vlr & 7)) * 8));
      }
#pragma unroll
      for (int mt = 0; mt < 4; ++mt)
#pragma unroll
        for (int nt = 0; nt < 4; ++nt)
          acc[mt][nt] = __builtin_amdgcn_mfma_f32_16x16x32_bf16(af[mt], bfr[nt], acc[mt][nt], 0, 0, 0);
    }
    __syncthreads();                   // drains prefetch vmcnt; buf^1 ready
    buf ^= 1;
  }

  if (panel < 2) {
    __bf16* dst = (panel == 0) ? qb : kb;
    const float scale = (panel == 0) ? INV_SQRT_K : 1.0f;
#pragma unroll
    for (int mt = 0; mt < 4; ++mt) {
      const int row = m0 + jl0 + mt * 16 + quad * 4;
#pragma unroll
      for (int nt = 0; nt < 4; ++nt) {
        const int col = vl0 + nt * 16 + cl;
        const float bs = bias[col];
#pragma unroll
        for (int r = 0; r < 4; ++r)
          dst[(size_t)(row + r) * Kk + col] = (__bf16)((acc[mt][nt][r] + bs) * scale);
      }
    }
  } else {
    const int b = m0 >> 11;            // 128-row blocks never straddle a batch
#pragma unroll
    for (int mt = 0; mt < 4; ++mt) {
      const int t0 = (m0 & (Tt - 1)) + jl0 + mt * 16 + quad * 4;
#pragma unroll
      for (int nt = 0; nt < 4; ++nt) {
        const int vcol = (panel - 2) * 128 + vl0 + nt * 16 + cl;
        const float bs = bias[vl0 + nt * 16 + cl];
        bf16x4 v4;
#pragma unroll
        for (int r = 0; r < 4; ++r) v4[r] = (__bf16)(acc[mt][nt][r] + bs);
        *(bf16x4*)(vT + (size_t)(b * Vv + vcol) * Tt + t0) = v4;
      }
    }
  }
}

// ---------------------------------------------------------------------------
// sexp v3: expS = exp(Q.K^T) for lower-tri 128x128 blocks.
//   (validated R5-R8; P-write XOR swizzle, batch = blockIdx.x)
// ---------------------------------------------------------------------------
__global__ __launch_bounds__(256, 2) void sexp_kernel(
    const __bf16* __restrict__ qb, const __bf16* __restrict__ kb,
    __bf16* __restrict__ expS, float* __restrict__ partialD)
{
  __shared__ __bf16 tiles[2 * 128 * 128];   // Qtile | Ktile; reused as fp32 P
  __shared__ float lcs[4][64];
  __bf16* Qtile = tiles;
  __bf16* Ktile = tiles + 128 * 128;
  float*  P     = (float*)tiles;            // 128x128 fp32 = 64 KB

  const int b = blockIdx.x, l = blockIdx.y;  // batch fast -> XCD = b
  int jt = 0, base = 0;
  while (base + jt + 1 <= l) { base += jt + 1; ++jt; }   // uniform, <=16 iters
  const int it = l - base;

  const int lane = threadIdx.x & 63, wave = threadIdx.x >> 6;
  const int cl = lane & 15, quad = lane >> 4;
  const int jl0 = (wave >> 1) * 64;
  const int il0 = (wave & 1) * 64;
  const size_t rowbase = (size_t)b * Tt;

  // staging: 4 rows per gload16 (16 chunks/row); lane L -> row +L>>4,
  // slot L&15 holds source chunk (L&15)^(row&7).
  {
    const int srow = lane >> 4;          // 0..3
    const int cslot = lane & 15;
    const __bf16* qsrc = qb + (rowbase + jt * 128) * Kk;
    const __bf16* ksrc = kb + (rowbase + it * 128) * Kk;
#pragma unroll
    for (int t = 0; t < 8; ++t) {
      const int r0 = wave * 32 + t * 4;
      const int row = r0 + srow;
      const int cg = (cslot ^ (row & 7)) * 8;
      gload16(qsrc + (size_t)row * Kk + cg, Qtile + r0 * 128);
      gload16(ksrc + (size_t)row * Kk + cg, Ktile + r0 * 128);
    }
  }
  __syncthreads();

  f32x4 acc[4][4];
#pragma unroll
  for (int mt = 0; mt < 4; ++mt)
#pragma unroll
    for (int nt = 0; nt < 4; ++nt) acc[mt][nt] = (f32x4){0.f, 0.f, 0.f, 0.f};

#pragma unroll
  for (int s = 0; s < 4; ++s) {
    bf16x8 af[4], bfr[4];
#pragma unroll
    for (int mt = 0; mt < 4; ++mt) {
      const int jlr = jl0 + mt * 16 + cl;
      af[mt] = *(const bf16x8*)(Qtile + jlr * 128 + (((s * 4 + quad) ^ (jlr & 7)) * 8));
    }
#pragma unroll
    for (int nt = 0; nt < 4; ++nt) {
      const int ilr = il0 + nt * 16 + cl;
      bfr[nt] = *(const bf16x8*)(Ktile + ilr * 128 + (((s * 4 + quad) ^ (ilr & 7)) * 8));
    }
#pragma unroll
    for (int mt = 0; mt < 4; ++mt)
#pragma unroll
      for (int nt = 0; nt < 4; ++nt)
        acc[mt][nt] = __builtin_amdgcn_mfma_f32_16x16x32_bf16(af[mt], bfr[nt], acc[mt][nt], 0, 0, 0);
  }
  __syncthreads();                       // tiles free -> reuse as P

  // masked exp -> fp32 P (swizzled writes) + column sums of rounded values
  const bool diag = (it == jt);
  float cs[4] = {0.f, 0.f, 0.f, 0.f};
#pragma unroll
  for (int mt = 0; mt < 4; ++mt) {
    const int jl = jl0 + mt * 16 + quad * 4;
#pragma unroll
    for (int nt = 0; nt < 4; ++nt) {
      const int il = il0 + nt * 16 + cl;
#pragma unroll
      for (int r = 0; r < 4; ++r) {
        float p = __expf(acc[mt][nt][r]);
        if (diag && il > (jl + r)) p = 0.f;   // mask i > j (same-tile coords)
        cs[nt] += (float)(__bf16)p;           // what pass B will consume
        const int row = jl + r;
        P[row * 128 + (il ^ (((row >> 2) & 1) << 4))] = p;
      }
    }
  }
#pragma unroll
  for (int nt = 0; nt < 4; ++nt) {
    cs[nt] += __shfl_xor(cs[nt], 16);
    cs[nt] += __shfl_xor(cs[nt], 32);
  }
  if (quad == 0) {
#pragma unroll
    for (int nt = 0; nt < 4; ++nt) lcs[wave][nt * 16 + cl] = cs[nt];
  }
  __syncthreads();

  // coalesced bf16 store: 4 rows per pass, lane L -> row +L>>4, 8 elems.
  __bf16* slot = expS + ((size_t)(b * NTRI + l)) * (128 * 128);
  {
    const int srow = lane >> 4;
    const int c0 = (lane & 15) * 8;
#pragma unroll
    for (int t = 0; t < 8; ++t) {
      const int row = wave * 32 + t * 4 + srow;
      const int c0p = c0 ^ (((row >> 2) & 1) << 4);
      const f32x4 p0 = *(const f32x4*)(P + row * 128 + c0p);
      const f32x4 p1 = *(const f32x4*)(P + row * 128 + c0p + 4);
      bf16x8 pb;
#pragma unroll
      for (int u = 0; u < 4; ++u) { pb[u] = (__bf16)p0[u]; pb[4 + u] = (__bf16)p1[u]; }
      *(bf16x8*)(slot + (size_t)row * 128 + c0) = pb;
    }
  }

  const int tid = threadIdx.x;
  if (tid < 128) {                      // block column c = tid
    const int w0 = (tid < 64) ? 0 : 1;  // waves {0,2} cols [0,64), {1,3} [64,128)
    const int lc = tid & 63;
    const float s = lcs[w0][lc] + lcs[w0 + 2][lc];
    partialD[((size_t)b * 16 + jt) * Tt + it * 128 + tid] = s;
  }
}

// ---------------------------------------------------------------------------
// dvscale: fused dreduce + vscale (R4/R8-validated; batch = blockIdx.x).
// ---------------------------------------------------------------------------
__global__ __launch_bounds__(256) void dvscale_kernel(
    const float* __restrict__ partialD, bf16x8* __restrict__ vT8)
{
  __shared__ float rec[32];
  const int b = blockIdx.x, ic = blockIdx.y;
  const int i0 = ic * 32;
  const int tid = threadIdx.x;
  if (tid < 32) {
    const int i = i0 + tid;
    float s = 0.f;
#pragma unroll
    for (int jt = 0; jt < 16; ++jt) s += partialD[((size_t)b * 16 + jt) * Tt + i];
    rec[tid] = 1.0f / s;
  }
  __syncthreads();
  // 4 consecutive 16B units per v-row (64B runs); v advances every 4 lanes.
  const int iu = tid & 3, v0 = tid >> 2;
#pragma unroll
  for (int p = 0; p < 4; ++p) {
    const int v = v0 + p * 64;
    const size_t idx = ((size_t)b * Vv + v) * (Tt / 8) + (i0 >> 3) + iu;
    bf16x8 x = vT8[idx];
    const int rb = iu * 8;
#pragma unroll
    for (int t = 0; t < 8; ++t) x[t] = (__bf16)((float)x[t] * rec[rb + t]);
    vT8[idx] = x;
  }
}

// ---------------------------------------------------------------------------
// pvgemm v9: unpaired 64-row strips, LPT dispatch, 4 blocks/CU (validated R8).
// ---------------------------------------------------------------------------
__global__ __launch_bounds__(256, 4) void pvgemm_kernel(
    const __bf16* __restrict__ expS, const __bf16* __restrict__ vT,
    float* __restrict__ out)
{
  __shared__ __bf16 At[2][64 * 64];    // [jlocal 64][k 64], chunks swizzled
  __shared__ __bf16 Bt[2][64 * 64];    // [vlocal 64][k 64], chunks swizzled
  const int b = blockIdx.x;            // XCD affinity (gridDim.x = 8)
  const int y = (int)blockIdx.y;       // 0..127
  const int jt64 = 31 - (y >> 2);      // long strips first (LPT)
  const int nq = y & 3;                // 64-col quarter
  const int lane = threadIdx.x & 63, wave = threadIdx.x >> 6;
  const int cl = lane & 15, quad = lane >> 4;
  const int jl0 = (wave >> 1) * 32;    // wave m-offset in tile
  const int vl0 = (wave & 1) * 32;     // wave n-offset in tile
  const int lrow = lane >> 3;
  const int lchunk = ((lane & 7) ^ lrow) * 8;      // element offset of 16B chunk
  const __bf16* vbase = vT + ((size_t)b * Vv + nq * 64) * Tt;

  const int jt128 = jt64 >> 1;
  const int rowoff = (jt64 & 1) * 64;             // row offset inside 128-tile
  const int ksteps = jt64 + 1;                    // BK=64 steps
  const size_t tribase = (size_t)(b * NTRI + (jt128 * (jt128 + 1)) / 2) * 16384;

  f32x4 acc[2][2];
#pragma unroll
  for (int mt = 0; mt < 2; ++mt)
#pragma unroll
    for (int nt = 0; nt < 2; ++nt) acc[mt][nt] = (f32x4){0.f, 0.f, 0.f, 0.f};

  // prologue: stage step 0 into buf 0  (kb=0: it128=0, col-half 0)
#pragma unroll
  for (int t = 0; t < 2; ++t) {
    const int r0 = wave * 16 + t * 8;
    gload16(expS + tribase + (size_t)(rowoff + r0 + lrow) * 128 + lchunk,
            At[0] + r0 * 64);
    gload16(vbase + (size_t)(r0 + lrow) * Tt + lchunk, Bt[0] + r0 * 64);
  }
  __syncthreads();                   // step 0 staged

  int buf = 0;
  for (int kb = 0; kb < ksteps; ++kb) {
    // ---- issue next step's stage into buf^1 (flies under compute) ----
    if (kb + 1 < ksteps) {
      const int kn = kb + 1;
      const __bf16* Ag = expS + tribase + (size_t)(kn >> 1) * 16384
                       + (size_t)rowoff * 128 + (kn & 1) * 64;
      const int i0n = kn * 64;
#pragma unroll
      for (int t = 0; t < 2; ++t) {
        const int r0 = wave * 16 + t * 8;
        gload16(Ag + (size_t)(r0 + lrow) * 128 + lchunk, At[buf ^ 1] + r0 * 64);
        gload16(vbase + (size_t)(r0 + lrow) * Tt + i0n + lchunk, Bt[buf ^ 1] + r0 * 64);
      }
    }
    // ---- compute current buffer ----
#pragma unroll
    for (int ks = 0; ks < 2; ++ks) {
      bf16x8 af[2], bfr[2];
#pragma unroll
      for (int mt = 0; mt < 2; ++mt) {
        const int jlr = jl0 + mt * 16 + cl;
        af[mt] = *(const bf16x8*)(At[buf] + jlr * 64 + (((ks * 4 + quad) ^ (jlr & 7)) * 8));
      }
#pragma unroll
      for (int nt = 0; nt < 2; ++nt) {
        const int vlr = vl0 + nt * 16 + cl;
        bfr[nt] = *(const bf16x8*)(Bt[buf] + vlr * 64 + (((ks * 4 + quad) ^ (vlr & 7)) * 8));
      }
#pragma unroll
      for (int mt = 0; mt < 2; ++mt)
#pragma unroll
        for (int nt = 0; nt < 2; ++nt)
          acc[mt][nt] = __builtin_amdgcn_mfma_f32_16x16x32_bf16(af[mt], bfr[nt], acc[mt][nt], 0, 0, 0);
    }
    __syncthreads();                 // drains prefetch vmcnt; buf^1 ready
    buf ^= 1;
  }

  // ---- epilogue: fp32 stores to out[:, 256:512] (disjoint region) ----
  float* orow = out + ((size_t)b * Tt + jt64 * 64 + jl0) * (size_t)(Cc + Vv)
              + Cc + nq * 64 + vl0;
#pragma unroll
  for (int mt = 0; mt < 2; ++mt)
#pragma unroll
    for (int nt = 0; nt < 2; ++nt)
#pragma unroll
      for (int r = 0; r < 4; ++r)
        orow[(size_t)(mt * 16 + quad * 4 + r) * (Cc + Vv) + nt * 16 + cl] = acc[mt][nt][r];
}

// ---------------------------------------------------------------------------
extern "C" void kernel_launch(void* const* d_in, const int* in_sizes, int n_in,
                              void* d_out, int out_size, void* d_ws, size_t ws_size,
                              hipStream_t stream) {
  const float* inp  = (const float*)d_in[0];
  const float* feat = (const float*)d_in[1];
  const float* Wq   = (const float*)d_in[2];
  const float* bq   = (const float*)d_in[3];
  const float* Wk   = (const float*)d_in[4];
  const float* bk   = (const float*)d_in[5];
  const float* Wv   = (const float*)d_in[6];
  const float* bv   = (const float*)d_in[7];
  float* out = (float*)d_out;

  // ws layout (~71 MB):
  //  inpB 8M | featB 8M | qb 4M | kb 4M | vT 8M | Wqt/Wkt/Wvt 320K |
  //  partialD 2M @33M | expS 34.8M @36M
  char* ws = (char*)d_ws;
  __bf16* inpB   = (__bf16*)(ws);
  __bf16* featB  = (__bf16*)(ws + (8u << 20));
  __bf16* qb     = (__bf16*)(ws + (16u << 20));
  __bf16* kb     = (__bf16*)(ws + (20u << 20));
  __bf16* vT     = (__bf16*)(ws + (24u << 20));
  __bf16* Wqt    = (__bf16*)(ws + (32u << 20));
  __bf16* Wkt    = (__bf16*)(ws + (32u << 20) + (128u << 10));
  __bf16* Wvt    = (__bf16*)(ws + (32u << 20) + (192u << 10));
  float*  partialD = (float*)(ws + (33u << 20));
  __bf16* expS     = (__bf16*)(ws + (36u << 20));

  prepw_kernel<<<dim3(4096 + 640), 256, 0, stream>>>(
      (const float4*)inp, (const float4*)feat, (float4*)out,
      (bf16x4*)inpB, (bf16x4*)featB, Wq, Wk, Wv, Wqt, Wkt, Wvt);
  qkv_mfma_kernel<<<dim3(BT / 128, 4), 256, 0, stream>>>(
      inpB, featB, Wqt, Wkt, Wvt, bq, bk, bv, qb, kb, vT);
  sexp_kernel<<<dim3(Bb, NTRI), 256, 0, stream>>>(qb, kb, expS, partialD);
  dvscale_kernel<<<dim3(Bb, 64), 256, 0, stream>>>(partialD, (bf16x8*)vT);
  pvgemm_kernel<<<dim3(Bb, 128), 256, 0, stream>>>(expS, vT, out);
}